// Round 6
// baseline (1504.456 us; speedup 1.0000x reference)
//
#include <hip/hip_runtime.h>

#define NC 512   // N_CLUSTERS

// ===========================================================================
// Pre-pass: convT[w][s] = (u16)conv_lut[s][w]  (verified R3/R5).
// ===========================================================================
__global__ __launch_bounds__(256) void k_transpose_pack(
    const int* __restrict__ src, unsigned short* __restrict__ dst)
{
    __shared__ unsigned short tile[64][65];
    int tx = blockIdx.x % 8, ty = blockIdx.x / 8;
    int lane = threadIdx.x & 63, grp = threadIdx.x >> 6;
    for (int r = grp * 16; r < grp * 16 + 16; ++r)
        tile[r][lane] = (unsigned short)src[(ty * 64 + r) * NC + tx * 64 + lane];
    __syncthreads();
    for (int r = grp * 16; r < grp * 16 + 16; ++r)
        dst[(tx * 64 + r) * NC + ty * 64 + lane] = tile[lane][r];
}

// add16[i][j] = (u16)add_lut[i][j]  (verified R3).
__global__ __launch_bounds__(256) void k_pack_add(
    const int* __restrict__ src, unsigned short* __restrict__ dst)
{
    int base = blockIdx.x * 1024 + threadIdx.x;
    for (int i = 0; i < 4; ++i) dst[base + i * 256] = (unsigned short)src[base + i * 256];
}

// ===========================================================================
// Stage 1: discretize -> u16 symbols (verified R1/R5).
// ===========================================================================
__global__ __launch_bounds__(256) void k_discretize(
    const float* __restrict__ x, const float* __restrict__ cent,
    unsigned short* __restrict__ out)
{
    __shared__ float c[NC];
    int tid = threadIdx.x;
    for (int i = tid; i < NC; i += 256) c[i] = cent[i];
    __syncthreads();
    int id = blockIdx.x * 256 + tid;   // 131072 exact
    float px = x[id];
    float best = fabsf(px - c[0]);
    int bi = 0;
    for (int k = 1; k < NC; ++k) {
        float d = fabsf(px - c[k]);
        if (d < best) { best = d; bi = k; }
    }
    out[id] = (unsigned short)bi;
}

// ===========================================================================
// Register-window pop-min scanner — R2 verbatim (verified).
// ===========================================================================
struct ScanU8 {
    unsigned char* base;
    uint32_t w[8];
    uint32_t mask;
    int chunk;

    static __device__ inline uint32_t nz4(uint32_t x) {
        uint32_t y = (x & 0x7F7F7F7Fu) + 0x7F7F7F7Fu;
        y = (y | x) & 0x80808080u;
        return (y * 0x00204081u) >> 28;
    }
    __device__ inline void init(unsigned char* b) { base = b; mask = 0; chunk = -1; }
    __device__ inline void load() {
        const uint4* p = (const uint4*)(base + chunk * 32);
        uint4 a = p[0], b2 = p[1];
        w[0]=a.x; w[1]=a.y; w[2]=a.z; w[3]=a.w;
        w[4]=b2.x; w[5]=b2.y; w[6]=b2.z; w[7]=b2.w;
        mask =  nz4(w[0])        | (nz4(w[1]) << 4)  | (nz4(w[2]) << 8)  | (nz4(w[3]) << 12)
             | (nz4(w[4]) << 16) | (nz4(w[5]) << 20) | (nz4(w[6]) << 24) | (nz4(w[7]) << 28);
    }
    __device__ inline void ensure() { while (mask == 0) { ++chunk; load(); } }
    __device__ inline int  peek()   { ensure(); return chunk * 32 + (int)__builtin_ctz(mask); }
    __device__ inline void consume_min() {
        int k = (int)__builtin_ctz(mask);
        int dw = k >> 2, sh = (k & 3) << 3;
        uint32_t cnt = 0;
#pragma unroll
        for (int i = 0; i < 8; ++i) if (i == dw) { cnt = (w[i] >> sh) & 0xFFu; w[i] -= (1u << sh); }
        if (cnt == 1) mask &= ~(1u << k);
    }
    __device__ inline int pop() { int v = peek(); consume_min(); return v; }
    __device__ inline void insert(int v) {
        int rel = v - chunk * 32;
        if (rel < 32) {
            int dw = rel >> 2, sh = (rel & 3) << 3;
#pragma unroll
            for (int i = 0; i < 8; ++i) if (i == dw) w[i] += (1u << sh);
            mask |= (1u << rel);
        } else {
            base[v] = (unsigned char)(base[v] + 1);
        }
    }
};

// ===========================================================================
// Symbolic conv, _conv_reduce semantics (fold verified R1/R2/R5).
// Block = (one co) x (64 positions); uniform-row builds (R5).
// WIN: fold gathers replaced by LDS-streamed add16 windows (pops ascend =>
// forward-only 32-row window; inserts go to bins, never rewind).
// ===========================================================================
template<typename IT, typename OT, int CIN, int CO, int IH, int IW, int OH, int OW, bool WIN>
__device__ __forceinline__ void conv_body(
    const IT* __restrict__ in_sym,              // (B, IH, IW, CIN)
    const int* __restrict__ wsym,               // (25*CIN, CO)
    const unsigned short* __restrict__ convT,   // (NC, NC) [w][s]
    const int* __restrict__ add_lut,            // (NC, NC) int   (direct fold)
    const unsigned short* __restrict__ add16,   // (NC, NC) u16   (windowed fold)
    const int* __restrict__ bias_lut,           // (NC, CO)
    const int* __restrict__ relu_lut,           // (NC,)
    OT* __restrict__ out)                       // (B, OH, OW, CO)
{
    constexpr int N   = 25 * CIN;
    constexpr int PPI = OH * OW;
    constexpr int BPC = (128 * PPI) / 64;       // blocks per co (exact)
    __shared__ __align__(16) unsigned char bins[64 * NC];        // 32 KB
    __shared__ __align__(16) unsigned short win[WIN ? 32 * NC : 8]; // 32 KB if WIN
    int tid = threadIdx.x;

    uint32_t* bz = (uint32_t*)bins;
    for (int i = 0; i < 128; ++i) bz[i * 64 + tid] = 0u;    // lane-private, 1 wave

    int posg = blockIdx.x % BPC;
    int co   = blockIdx.x / BPC;                // wave-uniform
    int pos  = posg * 64 + tid;
    int b  = pos / PPI;
    int yx = pos % PPI;
    int oy = yx / OW, ox = yx % OW;

    unsigned char* mybins = bins + tid * NC;
    for (int n = 0; n < N; ++n) {
        int i   = n / (5 * CIN);
        int rem = n % (5 * CIN);
        int j   = rem / CIN;
        int c   = rem % CIN;
        int s = (int)in_sym[((b * IH + (oy * 2 + i)) * IW + (ox * 2 + j)) * CIN + c];
        int w = wsym[n * CO + co];              // scalar (uniform)
        int g = convT[w * NC + s];              // uniform 1KB row
        mybins[g] = (unsigned char)(mybins[g] + 1);
    }

    ScanU8 sc; sc.init(mybins);
    int t = sc.pop();
    if (WIN) {
        int j = 1;
        int x = sc.pop();
        for (int r0 = 0; r0 < NC; r0 += 32) {
            const uint4* gsrc = (const uint4*)(add16 + r0 * NC);   // 32KB window
            uint4* wdst = (uint4*)win;
            for (int i = 0; i < 32; ++i) wdst[i * 64 + tid] = gsrc[i * 64 + tid];
            __syncthreads();
            while (j < N && x < r0 + 32) {
                int t2 = win[(x - r0) * NC + t];
                if (j < N - 2) {
                    int y = sc.peek();
                    if (t2 > y) { sc.consume_min(); sc.insert(t2); t = y; }
                    else t = t2;
                } else t = t2;
                ++j;
                if (j < N) x = sc.pop();
            }
            __syncthreads();
        }
    } else {
        for (int j = 1; j < N; ++j) {
            int x = sc.pop();
            int t2 = add_lut[x * NC + t];
            if (j < N - 2) {
                int y = sc.peek();
                if (t2 > y) { sc.consume_min(); sc.insert(t2); t = y; }
                else t = t2;
            } else t = t2;
        }
    }
    out[pos * CO + co] = (OT)relu_lut[bias_lut[t * CO + co]];
}

__global__ __launch_bounds__(64) void k_conv1(
    const unsigned short* in, const int* wsym, const unsigned short* convT,
    const int* add_lut, const unsigned short* add16,
    const int* bias, const int* relu, unsigned short* out)
{
    conv_body<unsigned short, unsigned short, 1, 6, 32, 32, 14, 14, false>(
        in, wsym, convT, add_lut, add16, bias, relu, out);
}

__global__ __launch_bounds__(64) void k_conv2(
    const unsigned short* in, const int* wsym, const unsigned short* convT,
    const int* add_lut, const unsigned short* add16,
    const int* bias, const int* relu, int* out)
{
    conv_body<unsigned short, int, 6, 16, 14, 14, 5, 5, true>(
        in, wsym, convT, add_lut, add16, bias, relu, out);
}

// ===========================================================================
// Symbolic FC, _fc_reduce = ascending pops (verified R1/R2). WIN: streamed
// add16 windows (this exact windowed fold passed correctness in R3).
// ===========================================================================
template<int M, int K, bool PERM, bool WIN>
__device__ __forceinline__ void fc_body(
    const int* __restrict__ in_sym,
    const int* __restrict__ wsym,      // (M, K)
    const int* __restrict__ fc_lut,    // (NC, NC)
    const int* __restrict__ add_lut,   // (NC, NC)
    const unsigned short* __restrict__ add16,
    const int* __restrict__ bias_lut,  // (NC, M)
    const int* __restrict__ relu_lut,  // (NC,)
    int* __restrict__ out)             // (B, M)
{
    __shared__ __align__(16) unsigned char bins[64 * NC];           // 32 KB
    __shared__ __align__(16) unsigned short win[WIN ? 32 * NC : 8]; // 32 KB if WIN
    int tid = threadIdx.x;
    uint32_t* bz = (uint32_t*)bins;
    for (int i = 0; i < 128; ++i) bz[i * 64 + tid] = 0u;

    int id = blockIdx.x * 64 + tid;
    int m = id % M;
    int b = id / M;

    unsigned char* mybins = bins + tid * NC;
    for (int k = 0; k < K; ++k) {
        int xaddr;
        if (PERM) { int c = k / 25, yx = k % 25; xaddr = b * 400 + yx * 16 + c; }
        else      { xaddr = b * K + k; }
        int v = fc_lut[in_sym[xaddr] * NC + wsym[m * K + k]];
        mybins[v] = (unsigned char)(mybins[v] + 1);
    }

    ScanU8 sc; sc.init(mybins);
    int t = sc.pop();
    if (WIN) {
        int remaining = K - 1;
        int x = sc.pop();
        bool have = true;
        for (int r0 = 0; r0 < NC; r0 += 32) {
            const uint4* gsrc = (const uint4*)(add16 + r0 * NC);
            uint4* wdst = (uint4*)win;
            for (int i = 0; i < 32; ++i) wdst[i * 64 + tid] = gsrc[i * 64 + tid];
            __syncthreads();
            while (have && x < r0 + 32) {
                t = win[(x - r0) * NC + t];
                if (--remaining > 0) x = sc.pop(); else have = false;
            }
            __syncthreads();
        }
    } else {
        for (int s = 1; s < K; ++s) t = add_lut[sc.pop() * NC + t];
    }
    out[id] = relu_lut[bias_lut[t * M + m]];
}

__global__ __launch_bounds__(64) void k_fc1(
    const int* in, const int* wsym, const int* fc_lut, const int* add_lut,
    const unsigned short* add16, const int* bias, const int* relu, int* out)
{
    fc_body<120, 400, true, true>(in, wsym, fc_lut, add_lut, add16, bias, relu, out);
}

__global__ __launch_bounds__(64) void k_fc2(
    const int* in, const int* wsym, const int* fc_lut, const int* add_lut,
    const unsigned short* add16, const int* bias, const int* relu, int* out)
{
    fc_body<84, 120, false, false>(in, wsym, fc_lut, add_lut, add16, bias, relu, out);
}

// ===========================================================================
// Head — verified R1.
// ===========================================================================
__global__ __launch_bounds__(64) void k_head(
    const int* __restrict__ f2_syms,   // (128, 84)
    const float* __restrict__ cent,    // (NC,)
    const float* __restrict__ w,       // (10, 84)
    const float* __restrict__ bias,    // (10,)
    float* __restrict__ out)           // (128, 10)
{
    int b = blockIdx.x * 64 + threadIdx.x;
    float acc[10];
#pragma unroll
    for (int o = 0; o < 10; ++o) acc[o] = bias[o];
    for (int k = 0; k < 84; ++k) {
        float f = cent[f2_syms[b * 84 + k]];
#pragma unroll
        for (int o = 0; o < 10; ++o) acc[o] += f * w[o * 84 + k];
    }
    float mx = acc[0];
#pragma unroll
    for (int o = 1; o < 10; ++o) mx = fmaxf(mx, acc[o]);
    float s = 0.f;
#pragma unroll
    for (int o = 0; o < 10; ++o) { acc[o] = expf(acc[o] - mx); s += acc[o]; }
    float inv = 1.f / s;
#pragma unroll
    for (int o = 0; o < 10; ++o) out[b * 10 + o] = acc[o] * inv;
}

// ===========================================================================
extern "C" void kernel_launch(void* const* d_in, const int* in_sizes, int n_in,
                              void* d_out, int out_size, void* d_ws, size_t ws_size,
                              hipStream_t stream)
{
    const float* x_bat  = (const float*)d_in[0];
    const float* cent   = (const float*)d_in[1];
    const int* conv_lut = (const int*)d_in[2];
    const int* fc_lut   = (const int*)d_in[3];
    const int* add_lut  = (const int*)d_in[4];
    const int* relu_lut = (const int*)d_in[5];
    const int* c1_bias  = (const int*)d_in[6];
    const int* c2_bias  = (const int*)d_in[7];
    const int* f1_bias  = (const int*)d_in[8];
    const int* f2_bias  = (const int*)d_in[9];
    const int* c1f      = (const int*)d_in[10];
    const int* c2f      = (const int*)d_in[11];
    const int* f1f      = (const int*)d_in[12];
    const int* f2f      = (const int*)d_in[13];
    const float* fc3_w  = (const float*)d_in[14];
    const float* fc3_b  = (const float*)d_in[15];
    float* out = (float*)d_out;

    char* ws = (char*)d_ws;
    unsigned short* convT = (unsigned short*)(ws);            // 512 KB
    unsigned short* add16 = (unsigned short*)(ws + 524288);   // 512 KB
    unsigned short* sym0  = (unsigned short*)(ws + 1048576);  // 256 KB
    unsigned short* c1o   = (unsigned short*)(ws + 1310720);  // 294 KB (u16)
    int* c2o = (int*)(ws + 1310720 + 301056);                 // 200 KB
    int* f1o = (int*)(ws + 1310720 + 301056 + 204800);        //  60 KB
    int* f2o = (int*)(ws + 1310720 + 301056 + 204800 + 61440);//  42 KB
    // peak ws ~1.92 MB

    k_transpose_pack<<<64, 256, 0, stream>>>(conv_lut, convT);
    k_pack_add<<<256, 256, 0, stream>>>(add_lut, add16);
    k_discretize<<<512, 256, 0, stream>>>(x_bat, cent, sym0);
    // conv1: 6 co x 392 pos-groups — R5 control (direct fold)
    k_conv1<<<2352, 64, 0, stream>>>(sym0, c1f, convT, add_lut, add16,
                                     c1_bias, relu_lut, c1o);
    // conv2: 16 co x 50 pos-groups — WINDOWED fold
    k_conv2<<<800, 64, 0, stream>>>(c1o, c2f, convT, add_lut, add16,
                                    c2_bias, relu_lut, c2o);
    // fc1: WINDOWED fold
    k_fc1<<<240, 64, 0, stream>>>(c2o, f1f, fc_lut, add_lut, add16,
                                  f1_bias, relu_lut, f1o);
    // fc2: direct fold (control)
    k_fc2<<<168, 64, 0, stream>>>(f1o, f2f, fc_lut, add_lut, add16,
                                  f2_bias, relu_lut, f2o);
    k_head<<<2, 64, 0, stream>>>(f2o, cent, fc3_w, fc3_b, out);
}

// Round 7
// 757.591 us; speedup vs baseline: 1.9858x; 1.9858x over previous
//
#include <hip/hip_runtime.h>

#define NC 512   // N_CLUSTERS

// ===========================================================================
// Pre-pass: dstT[w][s] = (u16)src[s][w]  (transpose verified R3/R5/R6).
// ===========================================================================
__global__ __launch_bounds__(256) void k_transpose_pack(
    const int* __restrict__ src, unsigned short* __restrict__ dst)
{
    __shared__ unsigned short tile[64][65];
    int tx = blockIdx.x % 8, ty = blockIdx.x / 8;
    int lane = threadIdx.x & 63, grp = threadIdx.x >> 6;
    for (int r = grp * 16; r < grp * 16 + 16; ++r)
        tile[r][lane] = (unsigned short)src[(ty * 64 + r) * NC + tx * 64 + lane];
    __syncthreads();
    for (int r = grp * 16; r < grp * 16 + 16; ++r)
        dst[(tx * 64 + r) * NC + ty * 64 + lane] = tile[lane][r];
}

// ===========================================================================
// Stage 1: discretize -> u16 symbols (verified R1/R5/R6).
// ===========================================================================
__global__ __launch_bounds__(256) void k_discretize(
    const float* __restrict__ x, const float* __restrict__ cent,
    unsigned short* __restrict__ out)
{
    __shared__ float c[NC];
    int tid = threadIdx.x;
    for (int i = tid; i < NC; i += 256) c[i] = cent[i];
    __syncthreads();
    int id = blockIdx.x * 256 + tid;   // 131072 exact
    float px = x[id];
    float best = fabsf(px - c[0]);
    int bi = 0;
    for (int k = 1; k < NC; ++k) {
        float d = fabsf(px - c[k]);
        if (d < best) { best = d; bi = k; }
    }
    out[id] = (unsigned short)bi;
}

// ===========================================================================
// Nibble-bin pop-min scanner (logic verified R4; insert() de-atomicized for
// redundant-lane folds: 4 lanes same addr/value plain RMW => net +1).
// 512 bins packed 8/word; window = 4 VGPRs (32 bins) + nonzero mask.
// ===========================================================================
struct ScanN {
    uint32_t* base;    // instance's 64-word nibble-bin region
    uint32_t w[4];
    uint32_t mask;     // bit k <=> bin (chunk*32+k) nonzero
    int chunk;

    static __device__ inline uint32_t nz4b(uint32_t x) {   // byte-nonzero -> 4 bits
        uint32_t y = (x & 0x7F7F7F7Fu) + 0x7F7F7F7Fu;
        y = (y | x) & 0x80808080u;
        return (y * 0x00204081u) >> 28;
    }
    static __device__ inline uint32_t spread4(uint32_t v) {
        v = (v | (v << 2)) & 0x33u;
        v = (v | (v << 1)) & 0x55u;
        return v;
    }
    static __device__ inline uint32_t nzn(uint32_t x) {    // per-nibble nonzero -> 8 bits
        uint32_t lo = x & 0x0F0F0F0Fu;
        uint32_t hi = (x >> 4) & 0x0F0F0F0Fu;
        return spread4(nz4b(lo)) | (spread4(nz4b(hi)) << 1);
    }
    __device__ inline void init(uint32_t* b) { base = b; mask = 0; chunk = -1; }
    __device__ inline void load() {
        uint4 a = *(const uint4*)(base + chunk * 4);   // 16B-aligned (stride 68 wds)
        w[0] = a.x; w[1] = a.y; w[2] = a.z; w[3] = a.w;
        mask = nzn(w[0]) | (nzn(w[1]) << 8) | (nzn(w[2]) << 16) | (nzn(w[3]) << 24);
    }
    __device__ inline void ensure() { while (mask == 0) { ++chunk; load(); } }
    __device__ inline int  peek()   { ensure(); return chunk * 32 + (int)__builtin_ctz(mask); }
    __device__ inline void consume_min() {          // precondition: mask != 0
        int k = (int)__builtin_ctz(mask);
        int dw = k >> 3, sh = (k & 7) << 2;
        uint32_t cnt = 0;
#pragma unroll
        for (int i = 0; i < 4; ++i) if (i == dw) { cnt = (w[i] >> sh) & 0xFu; w[i] -= (1u << sh); }
        if (cnt == 1) mask &= ~(1u << k);
    }
    __device__ inline int pop() { int v = peek(); consume_min(); return v; }
    __device__ inline void insert(int v) {          // precondition: v > current min
        int rel = v - chunk * 32;
        if (rel < 32) {
            int dw = rel >> 3, sh = (rel & 7) << 2;
#pragma unroll
            for (int i = 0; i < 4; ++i) if (i == dw) w[i] += (1u << sh);
            mask |= (1u << rel);
        } else {
            // plain RMW: redundant lanes read same old, write same new => +1 once
            uint32_t old = base[v >> 3];
            base[v >> 3] = old + (1u << ((v & 7) << 2));
        }
    }
};

// ===========================================================================
// Cooperative symbolic conv, _conv_reduce semantics (fold logic verified
// R1/R2/R5; nibble bins verified R4). 64-thread block = 16 instances x 4
// lanes. Build: lanes split items (stride 4) via LDS nibble atomics, <=4
// distinct convT rows per gather. Fold: 4 lanes redundant per instance =>
// 16 distinct add_lut lines per wave-gather; 4x wave count overall.
// ===========================================================================
template<typename IT, typename OT, int CIN, int CO, int IH, int IW, int OH, int OW>
__device__ __forceinline__ void conv_body(
    const IT* __restrict__ in_sym,              // (B, IH, IW, CIN)
    const int* __restrict__ wsym,               // (25*CIN, CO)
    const unsigned short* __restrict__ convT,   // (NC, NC) [w][s]
    const int* __restrict__ add_lut,            // (NC, NC)
    const int* __restrict__ bias_lut,           // (NC, CO)
    const int* __restrict__ relu_lut,           // (NC,)
    OT* __restrict__ out)                       // (B, OH, OW, CO)
{
    constexpr int N    = 25 * CIN;
    constexpr int PPI  = OH * OW;
    constexpr int BPC  = (128 * PPI) / 16;      // blocks per co (exact)
    constexpr int STR  = 68;                    // words/instance (272B, 16B-aligned, bank-staggered)
    __shared__ __align__(16) uint32_t bins[16 * STR];   // 4.4 KB
    int tid = threadIdx.x;
    int il  = tid >> 2;                         // instance-in-block 0..15
    int sub = tid & 3;                          // redundancy/role index

    for (int i = tid; i < 16 * STR; i += 64) bins[i] = 0u;

    int posg = blockIdx.x % BPC;
    int co   = blockIdx.x / BPC;                // wave-uniform
    int pos  = posg * 16 + il;
    int b  = pos / PPI;
    int yx = pos % PPI;
    int oy = yx / OW, ox = yx % OW;

    uint32_t* mybins = bins + il * STR;
    __syncthreads();                            // bins zeroed (in-wave DS order anyway)

    for (int n = sub; n < N; n += 4) {          // 4 lanes split the N items
        int i   = n / (5 * CIN);
        int rem = n % (5 * CIN);
        int j   = rem / CIN;
        int c   = rem % CIN;
        int s = (int)in_sym[((b * IH + (oy * 2 + i)) * IW + (ox * 2 + j)) * CIN + c];
        int w = wsym[n * CO + co];              // <=4 distinct per wave-instr
        int g = convT[w * NC + s];              // <=4 distinct 1KB rows
        atomicAdd(&mybins[g >> 3], 1u << ((g & 7) << 2));
    }
    __syncthreads();                            // build visible before fold

    // Fold: all 4 lanes of an instance run the identical chain (lockstep).
    ScanN sc; sc.init(mybins);
    int t = sc.pop();
    for (int j = 1; j < N; ++j) {
        int x = sc.pop();
        int t2 = add_lut[x * NC + t];           // 16 distinct lines per wave
        if (j < N - 2) {
            int y = sc.peek();
            if (t2 > y) { sc.consume_min(); sc.insert(t2); t = y; }
            else t = t2;
        } else t = t2;
    }
    if (sub == 0)
        out[pos * CO + co] = (OT)relu_lut[bias_lut[t * CO + co]];
}

__global__ __launch_bounds__(64) void k_conv1(
    const unsigned short* in, const int* wsym, const unsigned short* convT,
    const int* add_lut, const int* bias, const int* relu, unsigned short* out)
{
    conv_body<unsigned short, unsigned short, 1, 6, 32, 32, 14, 14>(
        in, wsym, convT, add_lut, bias, relu, out);
}

__global__ __launch_bounds__(64) void k_conv2(
    const unsigned short* in, const int* wsym, const unsigned short* convT,
    const int* add_lut, const int* bias, const int* relu, int* out)
{
    conv_body<unsigned short, int, 6, 16, 14, 14, 5, 5>(
        in, wsym, convT, add_lut, bias, relu, out);
}

// ===========================================================================
// Cooperative symbolic FC, _fc_reduce = ascending pops (verified R1/R2).
// Block = one m (uniform) x 16 batch rows x 4 lanes. fcT rows <=4 distinct.
// PERM: fc1 reads c2o (b,5,5,16) with the (0,3,1,2)-flatten map (verified).
// Non-PERM reads the previous FC's m-major output [k][128+b].
// ===========================================================================
template<int M, int K, bool PERM>
__device__ __forceinline__ void fc_body(
    const int* __restrict__ in_sym,
    const int* __restrict__ wsym,      // (M, K)
    const unsigned short* __restrict__ fcT,  // (NC, NC) [w][x]
    const int* __restrict__ add_lut,   // (NC, NC)
    const int* __restrict__ bias_lut,  // (NC, M)
    const int* __restrict__ relu_lut,  // (NC,)
    int* __restrict__ out)             // (M, 128) m-major
{
    constexpr int STR = 68;
    __shared__ __align__(16) uint32_t bins[16 * STR];   // 4.4 KB
    int tid = threadIdx.x;
    int il  = tid >> 2;
    int sub = tid & 3;

    for (int i = tid; i < 16 * STR; i += 64) bins[i] = 0u;

    int m  = blockIdx.x / 8;                   // wave-uniform
    int bg = blockIdx.x % 8;
    int b  = bg * 16 + il;

    uint32_t* mybins = bins + il * STR;
    __syncthreads();

    for (int k = sub; k < K; k += 4) {
        int xaddr;
        if (PERM) { int c = k / 25, yx = k % 25; xaddr = b * 400 + yx * 16 + c; }
        else      { xaddr = k * 128 + b; }
        int x = in_sym[xaddr];
        int w = wsym[m * K + k];               // <=4 distinct per wave-instr
        int g = fcT[w * NC + x];               // <=4 distinct rows
        atomicAdd(&mybins[g >> 3], 1u << ((g & 7) << 2));
    }
    __syncthreads();

    ScanN sc; sc.init(mybins);
    int t = sc.pop();
    for (int s = 1; s < K; ++s) t = add_lut[sc.pop() * NC + t];
    if (sub == 0)
        out[m * 128 + b] = relu_lut[bias_lut[t * M + m]];
}

__global__ __launch_bounds__(64) void k_fc1(
    const int* in, const int* wsym, const unsigned short* fcT,
    const int* add_lut, const int* bias, const int* relu, int* out)
{
    fc_body<120, 400, true>(in, wsym, fcT, add_lut, bias, relu, out);
}

__global__ __launch_bounds__(64) void k_fc2(
    const int* in, const int* wsym, const unsigned short* fcT,
    const int* add_lut, const int* bias, const int* relu, int* out)
{
    fc_body<84, 120, false>(in, wsym, fcT, add_lut, bias, relu, out);
}

// ===========================================================================
// Head: feats = centroid[sym], logits @ W^T + b, softmax. Reads m-major f2.
// ===========================================================================
__global__ __launch_bounds__(64) void k_head(
    const int* __restrict__ f2m,       // (84, 128) m-major
    const float* __restrict__ cent,    // (NC,)
    const float* __restrict__ w,       // (10, 84)
    const float* __restrict__ bias,    // (10,)
    float* __restrict__ out)           // (128, 10)
{
    int b = blockIdx.x * 64 + threadIdx.x;
    float acc[10];
#pragma unroll
    for (int o = 0; o < 10; ++o) acc[o] = bias[o];
    for (int k = 0; k < 84; ++k) {
        float f = cent[f2m[k * 128 + b]];      // coalesced
#pragma unroll
        for (int o = 0; o < 10; ++o) acc[o] += f * w[o * 84 + k];
    }
    float mx = acc[0];
#pragma unroll
    for (int o = 1; o < 10; ++o) mx = fmaxf(mx, acc[o]);
    float s = 0.f;
#pragma unroll
    for (int o = 0; o < 10; ++o) { acc[o] = expf(acc[o] - mx); s += acc[o]; }
    float inv = 1.f / s;
#pragma unroll
    for (int o = 0; o < 10; ++o) out[b * 10 + o] = acc[o] * inv;
}

// ===========================================================================
extern "C" void kernel_launch(void* const* d_in, const int* in_sizes, int n_in,
                              void* d_out, int out_size, void* d_ws, size_t ws_size,
                              hipStream_t stream)
{
    const float* x_bat  = (const float*)d_in[0];
    const float* cent   = (const float*)d_in[1];
    const int* conv_lut = (const int*)d_in[2];
    const int* fc_lut   = (const int*)d_in[3];
    const int* add_lut  = (const int*)d_in[4];
    const int* relu_lut = (const int*)d_in[5];
    const int* c1_bias  = (const int*)d_in[6];
    const int* c2_bias  = (const int*)d_in[7];
    const int* f1_bias  = (const int*)d_in[8];
    const int* f2_bias  = (const int*)d_in[9];
    const int* c1f      = (const int*)d_in[10];
    const int* c2f      = (const int*)d_in[11];
    const int* f1f      = (const int*)d_in[12];
    const int* f2f      = (const int*)d_in[13];
    const float* fc3_w  = (const float*)d_in[14];
    const float* fc3_b  = (const float*)d_in[15];
    float* out = (float*)d_out;

    char* ws = (char*)d_ws;
    unsigned short* convT = (unsigned short*)(ws);            // 512 KB
    unsigned short* fcT   = (unsigned short*)(ws + 524288);   // 512 KB
    unsigned short* sym0  = (unsigned short*)(ws + 1048576);  // 256 KB
    unsigned short* c1o   = (unsigned short*)(ws + 1310720);  // 294 KB (b,14,14,6) u16
    int* c2o = (int*)(ws + 1611776);                          // 200 KB (b,5,5,16)
    int* f1o = (int*)(ws + 1816576);                          //  60 KB (120,128) m-major
    int* f2o = (int*)(ws + 1878016);                          //  42 KB (84,128)  m-major
    // peak ws ~1.92 MB (< R3's proven 2.29 MB)

    k_transpose_pack<<<64, 256, 0, stream>>>(conv_lut, convT);
    k_transpose_pack<<<64, 256, 0, stream>>>(fc_lut, fcT);
    k_discretize<<<512, 256, 0, stream>>>(x_bat, cent, sym0);
    // conv1: 6 co x 1568 pos-groups = 9408 blocks (16 inst each)
    k_conv1<<<9408, 64, 0, stream>>>(sym0, c1f, convT, add_lut, c1_bias, relu_lut, c1o);
    // conv2: 16 co x 200 pos-groups = 3200 blocks
    k_conv2<<<3200, 64, 0, stream>>>(c1o, c2f, convT, add_lut, c2_bias, relu_lut, c2o);
    // fc1: 120 m x 8 b-groups = 960 blocks
    k_fc1<<<960, 64, 0, stream>>>(c2o, f1f, fcT, add_lut, f1_bias, relu_lut, f1o);
    // fc2: 84 m x 8 b-groups = 672 blocks
    k_fc2<<<672, 64, 0, stream>>>(f1o, f2f, fcT, add_lut, f2_bias, relu_lut, f2o);
    k_head<<<2, 64, 0, stream>>>(f2o, cent, fc3_w, fc3_b, out);
}